// Round 7
// baseline (235.974 us; speedup 1.0000x reference)
//
#include <hip/hip_runtime.h>

#define Bc 1024
#define Tc 512
#define Ic 64
#define Hc 32
#define L2E2 2.8853900817779268f   // 2*log2(e): tanh(a) = 1 - 2/(2^(a*L2E2)+1)

// xt transpose tile: [2 buf][32 h][24 t-pitch] bf16 (16 used; 48B rows)
#define XT_ROW 24
#define XT_BUF (Hc * XT_ROW)       // 768 elems per buffer

typedef __bf16 bf16x8 __attribute__((ext_vector_type(8)));
typedef __bf16 bf16x4 __attribute__((ext_vector_type(4)));
typedef float  f32x4  __attribute__((ext_vector_type(4)));
typedef unsigned uint2v __attribute__((ext_vector_type(2)));

__device__ inline bf16x8 to_bf16x8(float4 u0, float4 u1) {
    bf16x8 t;
    t[0] = (__bf16)u0.x; t[1] = (__bf16)u0.y; t[2] = (__bf16)u0.z; t[3] = (__bf16)u0.w;
    t[4] = (__bf16)u1.x; t[5] = (__bf16)u1.y; t[6] = (__bf16)u1.z; t[7] = (__bf16)u1.w;
    return t;
}
__device__ inline bf16x8 to_bf16x8s(float4 u0, float4 u1, float s) {
    bf16x8 t;
    t[0] = (__bf16)(u0.x*s); t[1] = (__bf16)(u0.y*s); t[2] = (__bf16)(u0.z*s); t[3] = (__bf16)(u0.w*s);
    t[4] = (__bf16)(u1.x*s); t[5] = (__bf16)(u1.y*s); t[6] = (__bf16)(u1.z*s); t[7] = (__bf16)(u1.w*s);
    return t;
}

// ---------------------------------------------------------------------------
// R12: full-dot per lane + helper wave. Empirical law (R8-R11): wall ~=
// chain-links x ~21cy; cross-lane + trans links dominate. Half-dot schemes
// REQUIRE a repack swap (stored-set vs computed-h contradiction); full-dot
// does not: lane owns h = lane&31 (2 copies across wave), c_next = rr is a
// register rename. Chain: PLSWAP -> sel -> ror -> 4 fmaf -> 3 add -> exp2
// -> add -> rcp  (~12 links vs R11's ~17). All-f32 state+weights (absmax
// drops to the bf16-xq floor). The 76-inst/step issue cost is paid for by a
// HELPER WAVE (block=128): it owns the MFMA x-proj pipeline, pbuf reduce,
// and output stores; the scan wave issues only the chain. 1024 blocks x 2
// waves = 8 waves/CU. Barrier once per 16-step tile; buffer parities keep
// writer/reader disjoint within an iteration (helper: buf[tb&1]; scan
// prefetch: buf[(tb+1)&1]); pbuf double-buffered with opposite parity.
// ---------------------------------------------------------------------------

// DPP row-rotate-right by N within 16-lane rows (all lanes valid)
#define RORD(dst, src, N)                                                     \
    dst = (unsigned)__builtin_amdgcn_mov_dpp((int)(src), 0x120 + (N), 0xF, 0xF, false);

#if __has_builtin(__builtin_amdgcn_permlane16_swap)
#define PLSWAP(A, B)                                                          \
    { uint2v _t = __builtin_amdgcn_permlane16_swap((A), (B), false, false);   \
      (A) = _t[0]; (B) = _t[1]; }
#else
#define PLSWAP(A, B)                                                          \
    asm("s_nop 1\n\tv_permlane16_swap_b32 %0, %1" : "+v"(A), "+v"(B));
#endif

#define F32(u) __builtin_bit_cast(float, (u))

#define STEP(xv, uu)                                                          \
    {                                                                         \
        unsigned P0_ = c, P1_ = c;                                            \
        PLSWAP(P0_, P1_)                                                      \
        const unsigned cp = psel ? P0_ : P1_;                                 \
        unsigned o1,o2,o3,o4,o5,o6,o7,o8,o9,o10,o11,o12,o13,o14,o15;          \
        unsigned p1,p2,p3,p4,p5,p6,p7,p8,p9,p10,p11,p12,p13,p14,p15;          \
        RORD(o1,c,1)  RORD(o2,c,2)   RORD(o3,c,3)   RORD(o4,c,4)              \
        RORD(o5,c,5)  RORD(o6,c,6)   RORD(o7,c,7)   RORD(o8,c,8)              \
        RORD(o9,c,9)  RORD(o10,c,10) RORD(o11,c,11) RORD(o12,c,12)            \
        RORD(o13,c,13) RORD(o14,c,14) RORD(o15,c,15)                          \
        RORD(p1,cp,1)  RORD(p2,cp,2)   RORD(p3,cp,3)   RORD(p4,cp,4)          \
        RORD(p5,cp,5)  RORD(p6,cp,6)   RORD(p7,cp,7)   RORD(p8,cp,8)          \
        RORD(p9,cp,9)  RORD(p10,cp,10) RORD(p11,cp,11) RORD(p12,cp,12)        \
        RORD(p13,cp,13) RORD(p14,cp,14) RORD(p15,cp,15)                       \
        float a0 = fmaf(F32(c), Wo0, (xv));                                   \
        a0 = fmaf(F32(o1), Wo1, a0);                                          \
        a0 = fmaf(F32(o2), Wo2, a0);                                          \
        a0 = fmaf(F32(o3), Wo3, a0);                                          \
        float a1 = F32(o4) * Wo4;                                             \
        a1 = fmaf(F32(o5), Wo5, a1);                                          \
        a1 = fmaf(F32(o6), Wo6, a1);                                          \
        a1 = fmaf(F32(o7), Wo7, a1);                                          \
        float a2 = F32(o8) * Wo8;                                             \
        a2 = fmaf(F32(o9),  Wo9,  a2);                                        \
        a2 = fmaf(F32(o10), Wo10, a2);                                        \
        a2 = fmaf(F32(o11), Wo11, a2);                                        \
        float a3 = F32(o12) * Wo12;                                           \
        a3 = fmaf(F32(o13), Wo13, a3);                                        \
        a3 = fmaf(F32(o14), Wo14, a3);                                        \
        a3 = fmaf(F32(o15), Wo15, a3);                                        \
        float a4 = fmaf(F32(cp), Wp0, bch);                                   \
        a4 = fmaf(F32(p1), Wp1, a4);                                          \
        a4 = fmaf(F32(p2), Wp2, a4);                                          \
        a4 = fmaf(F32(p3), Wp3, a4);                                          \
        float a5 = F32(p4) * Wp4;                                             \
        a5 = fmaf(F32(p5), Wp5, a5);                                          \
        a5 = fmaf(F32(p6), Wp6, a5);                                          \
        a5 = fmaf(F32(p7), Wp7, a5);                                          \
        float a6 = F32(p8) * Wp8;                                             \
        a6 = fmaf(F32(p9),  Wp9,  a6);                                        \
        a6 = fmaf(F32(p10), Wp10, a6);                                        \
        a6 = fmaf(F32(p11), Wp11, a6);                                        \
        float a7 = F32(p12) * Wp12;                                           \
        a7 = fmaf(F32(p13), Wp13, a7);                                        \
        a7 = fmaf(F32(p14), Wp14, a7);                                        \
        a7 = fmaf(F32(p15), Wp15, a7);                                        \
        const float A_ = ((a0 + a1) + (a2 + a3)) + ((a4 + a5) + (a6 + a7));   \
        const float e_ = __builtin_amdgcn_exp2f(A_);                          \
        rr = __builtin_amdgcn_rcpf(e_ + 1.0f);                                \
        pb[(uu) * 36] = fmaf(rr, w2o, wo);                                    \
        c = __builtin_bit_cast(unsigned, rr);                                 \
    }

// bf16x8 -> two float4 (widening, exact)
#define CVT8(dlo, dhi, src)                                                   \
    dlo.x = (float)(src)[0]; dlo.y = (float)(src)[1];                         \
    dlo.z = (float)(src)[2]; dlo.w = (float)(src)[3];                         \
    dhi.x = (float)(src)[4]; dhi.y = (float)(src)[5];                         \
    dhi.z = (float)(src)[6]; dhi.w = (float)(src)[7];

// phase-1 tile: global loads -> regs (own batch b); helper wave only
#define TILE_LOAD(lt)                                                         \
    do {                                                                      \
        const float* xp_ = x + ((size_t)b * Tc + (lt) * 16 + m2) * Ic + r * 8;\
        Xa0 = ((const float4*)xp_)[0];                                        \
        Xa1 = ((const float4*)xp_)[1];                                        \
        Xa2 = ((const float4*)(xp_ + 32))[0];                                 \
        Xa3 = ((const float4*)(xp_ + 32))[1];                                 \
    } while (0)

// phase-1 tile: MFMA + bias + bf16 pack + LDS store into xt buffer `tp`
// (R7-verified D layout: col=lane&15 -> h, row=r*4+reg -> t-in-tile)
#define TILE_MFMA(tp)                                                         \
    do {                                                                      \
        const bf16x8 A0_ = to_bf16x8(Xa0, Xa1);                               \
        const bf16x8 A1_ = to_bf16x8(Xa2, Xa3);                               \
        f32x4 ac0 = {0.f, 0.f, 0.f, 0.f};                                     \
        f32x4 ac1 = {0.f, 0.f, 0.f, 0.f};                                     \
        ac0 = __builtin_amdgcn_mfma_f32_16x16x32_bf16(A0_, Bf[0][0], ac0, 0, 0, 0); \
        ac0 = __builtin_amdgcn_mfma_f32_16x16x32_bf16(A1_, Bf[0][1], ac0, 0, 0, 0); \
        ac1 = __builtin_amdgcn_mfma_f32_16x16x32_bf16(A0_, Bf[1][0], ac1, 0, 0, 0); \
        ac1 = __builtin_amdgcn_mfma_f32_16x16x32_bf16(A1_, Bf[1][1], ac1, 0, 0, 0); \
        bf16x4 p0_, p1_;                                                      \
        p0_[0] = (__bf16)(ac0[0] + bias0); p0_[1] = (__bf16)(ac0[1] + bias0); \
        p0_[2] = (__bf16)(ac0[2] + bias0); p0_[3] = (__bf16)(ac0[3] + bias0); \
        p1_[0] = (__bf16)(ac1[0] + bias1); p1_[1] = (__bf16)(ac1[1] + bias1); \
        p1_[2] = (__bf16)(ac1[2] + bias1); p1_[3] = (__bf16)(ac1[3] + bias1); \
        *(bf16x4*)&(tp)[m2 * XT_ROW + r * 4]        = p0_;                    \
        *(bf16x4*)&(tp)[(m2 + 16) * XT_ROW + r * 4] = p1_;                    \
    } while (0)

__global__ __launch_bounds__(128, 1) void fused_rnn_kernel(
    const float* __restrict__ x, const float* __restrict__ Wih,
    const float* __restrict__ bih, const float* __restrict__ h0,
    const float* __restrict__ Whh, const float* __restrict__ bhh,
    const float* __restrict__ Wout, const float* __restrict__ bout,
    float* __restrict__ out)
{
    __shared__ __bf16 xt[2 * XT_BUF];     // 3072 B  (double-buffered tiles)
    __shared__ float  pbuf[2][16][36];    // 4608 B  (double-buffered partials)

    const int tid  = threadIdx.x;
    const int wid  = tid >> 6;           // 0 = scan wave, 1 = helper wave
    const int lane = tid & 63;
    const int m2   = lane & 15;
    const int r    = lane >> 4;
    const int h31  = lane & 31;          // scan: owned output h (2 copies)
    const int b    = blockIdx.x;         // one batch per block

    // ---------------- declarations shared across the barrier loop ----------
    // helper-wave state
    bf16x8 Bf[2][2];
    float  bias0 = 0.f, bias1 = 0.f;
    float4 Xa0, Xa1, Xa2, Xa3;
    // scan-wave state
    bool  psel = false;
    float Wo0=0,Wo1=0,Wo2=0,Wo3=0,Wo4=0,Wo5=0,Wo6=0,Wo7=0,
          Wo8=0,Wo9=0,Wo10=0,Wo11=0,Wo12=0,Wo13=0,Wo14=0,Wo15=0,
          Wp0=0,Wp1=0,Wp2=0,Wp3=0,Wp4=0,Wp5=0,Wp6=0,Wp7=0,
          Wp8=0,Wp9=0,Wp10=0,Wp11=0,Wp12=0,Wp13=0,Wp14=0,Wp15=0;
    float bch = 0.f, wo = 0.f, w2o = 0.f, rr = 0.f;
    unsigned c = 0;
    bf16x8 na0, na1;
    float4 qa0, qa1, qa2, qa3;
    const float bo = bout[0];
    float* orow = out + (size_t)b * Tc;
    const __bf16* xrbase = xt + h31 * XT_ROW;

    if (wid == 1) {
        // ---- helper prologue: Wih fragments (pre-scaled by L2E2) ----------
#pragma unroll
        for (int nh = 0; nh < 2; ++nh)
#pragma unroll
            for (int kh = 0; kh < 2; ++kh) {
                const float* wp = Wih + (m2 + 16 * nh) * Ic + r * 8 + kh * 32;
                Bf[nh][kh] = to_bf16x8s(((const float4*)wp)[0],
                                        ((const float4*)wp)[1], L2E2);
            }
        bias0 = bih[m2] * L2E2;
        bias1 = bih[m2 + 16] * L2E2;
        TILE_LOAD(0); TILE_MFMA(xt);            // tile0 -> buf0
        TILE_LOAD(1); TILE_MFMA(xt + XT_BUF);   // tile1 -> buf1
        TILE_LOAD(2);                           // tile2 staged in regs
    } else {
        // ---- scan prologue: psel discovery (R9-proven) --------------------
        {
            unsigned d0 = (unsigned)lane, d1 = (unsigned)lane;
            PLSWAP(d0, d1)
            psel = (d0 == (unsigned)(lane ^ 16));
        }
        // ---- index simulation: identical network on h-payloads ------------
        const unsigned u = (unsigned)h31;
        unsigned up;
        { unsigned U0 = u, U1 = u; PLSWAP(U0, U1) up = psel ? U0 : U1; }
        unsigned so1,so2,so3,so4,so5,so6,so7,so8,so9,so10,so11,so12,so13,so14,so15;
        unsigned sp1,sp2,sp3,sp4,sp5,sp6,sp7,sp8,sp9,sp10,sp11,sp12,sp13,sp14,sp15;
        RORD(so1,u,1)  RORD(so2,u,2)   RORD(so3,u,3)   RORD(so4,u,4)
        RORD(so5,u,5)  RORD(so6,u,6)   RORD(so7,u,7)   RORD(so8,u,8)
        RORD(so9,u,9)  RORD(so10,u,10) RORD(so11,u,11) RORD(so12,u,12)
        RORD(so13,u,13) RORD(so14,u,14) RORD(so15,u,15)
        RORD(sp1,up,1)  RORD(sp2,up,2)   RORD(sp3,up,3)   RORD(sp4,up,4)
        RORD(sp5,up,5)  RORD(sp6,up,6)   RORD(sp7,up,7)   RORD(sp8,up,8)
        RORD(sp9,up,9)  RORD(sp10,up,10) RORD(sp11,up,11) RORD(sp12,up,12)
        RORD(sp13,up,13) RORD(sp14,up,14) RORD(sp15,up,15)
        // ---- per-lane permuted f32 weights (scaled -2*L2E2) ---------------
        const float cw = -2.0f * L2E2;
        const float* wrh = Whh + h31 * Hc;
        Wo0  = wrh[u]    * cw;
        Wo1  = wrh[so1]  * cw;  Wo2  = wrh[so2]  * cw;
        Wo3  = wrh[so3]  * cw;  Wo4  = wrh[so4]  * cw;
        Wo5  = wrh[so5]  * cw;  Wo6  = wrh[so6]  * cw;
        Wo7  = wrh[so7]  * cw;  Wo8  = wrh[so8]  * cw;
        Wo9  = wrh[so9]  * cw;  Wo10 = wrh[so10] * cw;
        Wo11 = wrh[so11] * cw;  Wo12 = wrh[so12] * cw;
        Wo13 = wrh[so13] * cw;  Wo14 = wrh[so14] * cw;
        Wo15 = wrh[so15] * cw;
        Wp0  = wrh[up]   * cw;
        Wp1  = wrh[sp1]  * cw;  Wp2  = wrh[sp2]  * cw;
        Wp3  = wrh[sp3]  * cw;  Wp4  = wrh[sp4]  * cw;
        Wp5  = wrh[sp5]  * cw;  Wp6  = wrh[sp6]  * cw;
        Wp7  = wrh[sp7]  * cw;  Wp8  = wrh[sp8]  * cw;
        Wp9  = wrh[sp9]  * cw;  Wp10 = wrh[sp10] * cw;
        Wp11 = wrh[sp11] * cw;  Wp12 = wrh[sp12] * cw;
        Wp13 = wrh[sp13] * cw;  Wp14 = wrh[sp14] * cw;
        Wp15 = wrh[sp15] * cw;
        // bias' = (bhh + rowsum(Whh)) * L2E2
        float rs = 0.f;
#pragma unroll
        for (int j = 0; j < Hc; ++j) rs += wrh[j];
        bch = (bhh[h31] + rs) * L2E2;
        wo  = Wout[h31];
        w2o = -2.0f * wo;
        // initial state r = (1 - h)/2
        rr = fmaf(-0.5f, h0[(size_t)b * Hc + h31], 0.5f);
        c  = __builtin_bit_cast(unsigned, rr);
    }
    __syncthreads();   // tiles 0,1 visible

    if (wid == 0) {
        // xvals for tile 0 (buf0) -- protected from helper's iter-0 write to
        // buf0 by the barrier below
        na0 = *(const bf16x8*)(xrbase);
        na1 = *(const bf16x8*)(xrbase + 8);
        CVT8(qa0, qa1, na0) CVT8(qa2, qa3, na1)
    }
    __syncthreads();

#pragma unroll 1
    for (int tb = 0; tb < Tc / 16; ++tb) {
        if (wid == 0) {
            // prefetch xvals for tile tb+1 from buf[(tb+1)&1]; helper is
            // writing buf[tb&1] this iteration -- disjoint. Clamp at end.
            const int tbn = (tb + 1 < Tc / 16) ? tb + 1 : tb;
            const __bf16* xr = xrbase + (tbn & 1) * XT_BUF;
            na0 = *(const bf16x8*)(xr);
            na1 = *(const bf16x8*)(xr + 8);

            float* pb = &pbuf[tb & 1][0][h31];
            STEP(qa0.x, 0)  STEP(qa0.y, 1)  STEP(qa0.z, 2)  STEP(qa0.w, 3)
            STEP(qa1.x, 4)  STEP(qa1.y, 5)  STEP(qa1.z, 6)  STEP(qa1.w, 7)
            STEP(qa2.x, 8)  STEP(qa2.y, 9)  STEP(qa2.z, 10) STEP(qa2.w, 11)
            STEP(qa3.x, 12) STEP(qa3.y, 13) STEP(qa3.z, 14) STEP(qa3.w, 15)

            CVT8(qa0, qa1, na0) CVT8(qa2, qa3, na1)
        } else {
            // tile tb+2 -> buf[(tb+2)&1] == buf[tb&1]; loads for tile tb+3
            if (tb + 2 < Tc / 16) { TILE_MFMA(xt + (tb & 1) * XT_BUF); }
            if (tb + 3 < Tc / 16) { TILE_LOAD(tb + 3); }
            // reduce pbuf of block tb-1 (opposite parity) -> out
            if (tb >= 1 && lane < 16) {
                const float4* pr = (const float4*)&pbuf[(tb - 1) & 1][lane][0];
                const float4 s0_ = pr[0], s1_ = pr[1], s2_ = pr[2], s3_ = pr[3];
                const float4 s4_ = pr[4], s5_ = pr[5], s6_ = pr[6], s7_ = pr[7];
                const float s =
                    ((((s0_.x + s0_.y) + (s0_.z + s0_.w)) +
                      ((s1_.x + s1_.y) + (s1_.z + s1_.w))) +
                     (((s2_.x + s2_.y) + (s2_.z + s2_.w)) +
                      ((s3_.x + s3_.y) + (s3_.z + s3_.w)))) +
                    ((((s4_.x + s4_.y) + (s4_.z + s4_.w)) +
                      ((s5_.x + s5_.y) + (s5_.z + s5_.w))) +
                     (((s6_.x + s6_.y) + (s6_.z + s6_.w)) +
                      ((s7_.x + s7_.y) + (s7_.z + s7_.w))));
                orow[(tb - 1) * 16 + lane] = s + bo;
            }
        }
        __syncthreads();
    }

    // epilogue: last pbuf block + h_last
    if (wid == 1 && lane < 16) {
        const float4* pr = (const float4*)&pbuf[(Tc / 16 - 1) & 1][lane][0];
        const float4 s0_ = pr[0], s1_ = pr[1], s2_ = pr[2], s3_ = pr[3];
        const float4 s4_ = pr[4], s5_ = pr[5], s6_ = pr[6], s7_ = pr[7];
        const float s =
            ((((s0_.x + s0_.y) + (s0_.z + s0_.w)) +
              ((s1_.x + s1_.y) + (s1_.z + s1_.w))) +
             (((s2_.x + s2_.y) + (s2_.z + s2_.w)) +
              ((s3_.x + s3_.y) + (s3_.z + s3_.w)))) +
            ((((s4_.x + s4_.y) + (s4_.z + s4_.w)) +
              ((s5_.x + s5_.y) + (s5_.z + s5_.w))) +
             (((s6_.x + s6_.y) + (s6_.z + s6_.w)) +
              ((s7_.x + s7_.y) + (s7_.z + s7_.w))));
        orow[(Tc / 16 - 1) * 16 + lane] = s + bo;
    }
    if (wid == 0 && lane < 32) {
        // h_last: [1, B, H] appended after outs [B, T, 1]; h = 1 - 2r
        out[(size_t)Bc * Tc + (size_t)b * Hc + lane] = fmaf(-2.0f, rr, 1.0f);
    }
}

extern "C" void kernel_launch(void* const* d_in, const int* in_sizes, int n_in,
                              void* d_out, int out_size, void* d_ws, size_t ws_size,
                              hipStream_t stream) {
    const float* x    = (const float*)d_in[0];
    const float* h0   = (const float*)d_in[1];
    const float* Wih  = (const float*)d_in[2];
    const float* bih  = (const float*)d_in[3];
    const float* Whh  = (const float*)d_in[4];
    const float* bhh  = (const float*)d_in[5];
    const float* Wout = (const float*)d_in[6];
    const float* bout = (const float*)d_in[7];
    float* out = (float*)d_out;

    fused_rnn_kernel<<<Bc, 128, 0, stream>>>(x, Wih, bih, h0, Whh, bhh,
                                             Wout, bout, out);
}